// Round 8
// baseline (160.829 us; speedup 1.0000x reference)
//
#include <hip/hip_runtime.h>

// class_aware_rgat — MI355X (round 7: resubmit of round-5/6; broker timeouts,
// kernel never measured).
//
// Live math (softmax over size-1 axis == 1 => MLP path dead):
//   v = perm[i];  out[i] = sum_l anEmbTab[anc[v,l]] + coe(v) * sum_l reEmb[rel[v,l]]
//   coe(v) = dot(classEmb[leaves[v,0]], Wc) + bc ;  out[i] = 0 if v == V
//
// Round-4 measured: 41.5 us, HBM 42%, VALU 18%, occ 60%, VGPR 36 -> nothing
// saturated; ~890 cy per 2-row tile vs ~300 L1 line-requests/tile => TA-bound.
// This round: (1) reEmb (8.7 KB) staged in LDS -> rel gathers leave the L1/TA
// path; (2) coeTab pre-kernel -> 512B classEmb gather + butterfly becomes one
// 4B load. Line-requests/tile ~300 -> ~160.

#define RG_V  50000
#define RG_L  8
#define RG_NR 17              // reEmb rows (NR+1)

typedef float f32x4_native __attribute__((ext_vector_type(4)));

__device__ __forceinline__ float4 f4add(float4 a, float4 b) {
    return make_float4(a.x + b.x, a.y + b.y, a.z + b.z, a.w + b.w);
}
__device__ __forceinline__ float4 f4fma(float s, float4 a, float4 b) {
    return make_float4(fmaf(s, a.x, b.x), fmaf(s, a.y, b.y),
                       fmaf(s, a.z, b.z), fmaf(s, a.w, b.w));
}
__device__ __forceinline__ float4 shfl_xor32_f4(float4 x) {
    return make_float4(__shfl_xor(x.x, 32, 64), __shfl_xor(x.y, 32, 64),
                       __shfl_xor(x.z, 32, 64), __shfl_xor(x.w, 32, 64));
}

// ---- pre-kernel: coeTab[w] = dot(classEmb[w], Wc) + bc, w in [0, V+1) ----
// One wave per row, float2/lane, fully coalesced stream of classEmb.
__global__ __launch_bounds__(256) void rgat_coe_kernel(
    const float* __restrict__ classEmb,   // (V+1, 128)
    const float* __restrict__ Wc,         // (128,)
    const float* __restrict__ bc,         // (1,)
    float*       __restrict__ coeTab)     // (V+1,)
{
    const int row = blockIdx.x * 4 + (threadIdx.x >> 6);
    if (row > RG_V) return;
    const int lane = threadIdx.x & 63;
    const float2 c = reinterpret_cast<const float2*>(classEmb)[row * 64 + lane];
    const float2 w = reinterpret_cast<const float2*>(Wc)[lane];
    float p = c.x * w.x + c.y * w.y;
    #pragma unroll
    for (int off = 32; off >= 1; off >>= 1)
        p += __shfl_xor(p, off, 64);
    if (lane == 0) coeTab[row] = p + bc[0];
}

// ---- main kernel: 2 rows/wave, anc gathers global (float4, half-wave row
// pairing), rel sums from LDS, coe from coeTab, nontemporal 1KiB store ----
__global__ __launch_bounds__(256) void rgat_main_kernel(
    const float* __restrict__ reEmb,      // (17, 128)
    const float* __restrict__ anEmbTab,   // (V+NA+1, 128)
    const float* __restrict__ coeTab,     // (V+1,)
    const int*  __restrict__ leaves,      // (V, 8)
    const int*  __restrict__ ancestors,   // (V, 8)
    const int*  __restrict__ relations,   // (V, 8)
    const int*  __restrict__ perm,        // (V+1,)
    float*      __restrict__ out)         // (V+1, 128)
{
    __shared__ float reSh[RG_NR * 128];   // 8704 B

    // cooperative LDS fill (reEmb is 544 float4, contiguous)
    {
        const float4* src = reinterpret_cast<const float4*>(reEmb);
        float4*       dst = reinterpret_cast<float4*>(reSh);
        for (int i = threadIdx.x; i < RG_NR * 32; i += 256) dst[i] = src[i];
    }
    __syncthreads();

    const int wid  = blockIdx.x * 4 + (threadIdx.x >> 6);
    const int row0 = wid * 2;
    if (row0 > RG_V) return;              // after the barrier (no divergent-exit UB)
    const int lane = threadIdx.x & 63;
    const int h    = lane >> 5;           // half: 0 -> row0 out / even-l gathers
    const int li   = lane & 31;           // float4 column within a 128-float row
    const bool have1 = (row0 + 1 <= RG_V);

    const int p0 = perm[row0];
    const int p1 = have1 ? perm[row0 + 1] : 0;
    const bool valid0 = (p0 < RG_V);
    const bool valid1 = have1 && (p1 < RG_V);
    const int v0 = valid0 ? p0 : 0;
    const int v1 = valid1 ? p1 : 0;

    // ---- index loads ----
    const int4* anc4 = reinterpret_cast<const int4*>(ancestors);
    const int4* rel4 = reinterpret_cast<const int4*>(relations);
    const int4 a00 = anc4[v0 * 2], a01 = anc4[v0 * 2 + 1];
    const int4 a10 = anc4[v1 * 2], a11 = anc4[v1 * 2 + 1];
    const int4 r00 = rel4[v0 * 2], r01 = rel4[v0 * 2 + 1];
    const int4 r10 = rel4[v1 * 2], r11 = rel4[v1 * 2 + 1];
    const int lv0 = leaves[v0 * RG_L];
    const int lv1 = leaves[v1 * RG_L];

    // per-lane parity selection (explicit ?:, no runtime array indexing)
    const int ia00 = h ? a00.y : a00.x, ia01 = h ? a00.w : a00.z;
    const int ia02 = h ? a01.y : a01.x, ia03 = h ? a01.w : a01.z;
    const int ia10 = h ? a10.y : a10.x, ia11 = h ? a10.w : a10.z;
    const int ia12 = h ? a11.y : a11.x, ia13 = h ? a11.w : a11.z;
    const int ir00 = h ? r00.y : r00.x, ir01 = h ? r00.w : r00.z;
    const int ir02 = h ? r01.y : r01.x, ir03 = h ? r01.w : r01.z;
    const int ir10 = h ? r10.y : r10.x, ir11 = h ? r10.w : r10.z;
    const int ir12 = h ? r11.y : r11.x, ir13 = h ? r11.w : r11.z;

    const float4* anT = reinterpret_cast<const float4*>(anEmbTab);
    const float4* reS = reinterpret_cast<const float4*>(reSh);

    // ---- anc gathers: global, 1KiB/instr (2 embedding rows per instruction) ----
    const float4 gA00 = anT[(size_t)ia00 * 32 + li];
    const float4 gA01 = anT[(size_t)ia01 * 32 + li];
    const float4 gA02 = anT[(size_t)ia02 * 32 + li];
    const float4 gA03 = anT[(size_t)ia03 * 32 + li];
    const float4 gA10 = anT[(size_t)ia10 * 32 + li];
    const float4 gA11 = anT[(size_t)ia11 * 32 + li];
    const float4 gA12 = anT[(size_t)ia12 * 32 + li];
    const float4 gA13 = anT[(size_t)ia13 * 32 + li];

    // coe: one 4B load per half (broadcast within half)
    const float coe = coeTab[h ? lv1 : lv0];

    // ---- rel sums from LDS (ds_read_b128; off the L1/TA path) ----
    const float4 gR00 = reS[ir00 * 32 + li];
    const float4 gR01 = reS[ir01 * 32 + li];
    const float4 gR02 = reS[ir02 * 32 + li];
    const float4 gR03 = reS[ir03 * 32 + li];
    const float4 gR10 = reS[ir10 * 32 + li];
    const float4 gR11 = reS[ir11 * 32 + li];
    const float4 gR12 = reS[ir12 * 32 + li];
    const float4 gR13 = reS[ir13 * 32 + li];

    // ---- parity-partial sums ----
    float4 accA0 = f4add(f4add(gA00, gA01), f4add(gA02, gA03));
    float4 accA1 = f4add(f4add(gA10, gA11), f4add(gA12, gA13));
    float4 accR0 = f4add(f4add(gR00, gR01), f4add(gR02, gR03));
    float4 accR1 = f4add(f4add(gR10, gR11), f4add(gR12, gR13));

    // ---- merge parities: one 32-xor swap serves both rows ----
    float4 oxA = shfl_xor32_f4(h ? accA0 : accA1);
    float4 oxR = shfl_xor32_f4(h ? accR0 : accR1);
    float4 myA = f4add(h ? accA1 : accA0, oxA);
    float4 myR = f4add(h ? accR1 : accR0, oxR);

    float4 res = f4fma(coe, myR, myA);
    const bool validOwn = h ? valid1 : valid0;
    if (!validOwn) res = make_float4(0.f, 0.f, 0.f, 0.f);

    // ---- full-wave contiguous 1KiB nontemporal store ----
    if (h == 0 || have1) {
        float4* dst = reinterpret_cast<float4*>(out) + (size_t)row0 * 32 + lane;
        __builtin_nontemporal_store(*reinterpret_cast<f32x4_native*>(&res),
                                    reinterpret_cast<f32x4_native*>(dst));
    }
}

extern "C" void kernel_launch(void* const* d_in, const int* in_sizes, int n_in,
                              void* d_out, int out_size, void* d_ws, size_t ws_size,
                              hipStream_t stream) {
    // 0 dxEmb (dead), 1 classEmb, 2 reEmb, 3 anEmbTab, 4-7 W1/b1/W2/b2 (dead),
    // 8 Wc, 9 bc, 10 leaves, 11 ancestors, 12 relations, 13 permute_index
    const float* classEmb  = (const float*)d_in[1];
    const float* reEmb     = (const float*)d_in[2];
    const float* anEmbTab  = (const float*)d_in[3];
    const float* Wc        = (const float*)d_in[8];
    const float* bc        = (const float*)d_in[9];
    const int*   leaves    = (const int*)d_in[10];
    const int*   ancestors = (const int*)d_in[11];
    const int*   relations = (const int*)d_in[12];
    const int*   perm      = (const int*)d_in[13];
    float*       out       = (float*)d_out;
    float*       coeTab    = (float*)d_ws;          // (V+1) floats = 200 KB scratch

    // pre-kernel: coefficient table (one wave per row)
    {
        const int blocks = (RG_V + 1 + 3) / 4;
        rgat_coe_kernel<<<blocks, 256, 0, stream>>>(classEmb, Wc, bc, coeTab);
    }
    // main kernel: 2 rows per wave
    {
        const int waves  = (RG_V + 1 + 1) / 2;
        const int blocks = (waves + 3) / 4;
        rgat_main_kernel<<<blocks, 256, 0, stream>>>(
            reEmb, anEmbTab, coeTab, leaves, ancestors, relations, perm, out);
    }
}

// Round 9
// 157.232 us; speedup vs baseline: 1.0229x; 1.0229x over previous
//
#include <hip/hip_runtime.h>

// class_aware_rgat — MI355X (round 8: single kernel again; coe pre-pass was
// net -6us. 4 rows/wave via 2-deep unroll, one int4 perm load, all idx loads
// issued up front; anc gathers float4 half-wave-paired, 1KiB/instr).
//
// Live math (softmax over size-1 axis == 1 => MLP path dead):
//   v = perm[i];  out[i] = sum_l anEmbTab[anc[v,l]] + coe(v) * sum_l reEmb[rel[v,l]]
//   coe(v) = dot(classEmb[leaves[v,0]], Wc) + bc ;  out[i] = 0 if v == V
//
// Measured history: r1 50us (1 row/wave f2) -> r4 41.5us (2 rows/wave f4).
// r5 split (coeTab+LDS rel): main ~40.5 inferred, +6us serial pre-pass => dead
// L1/TA theory. Current model: scattered 512B gather BW ceiling ~3.5TB/s with
// L3 cycled cold each iter by the harness's 256MB ws poison.

#define RG_V  50000
#define RG_L  8

typedef float f32x4_native __attribute__((ext_vector_type(4)));

__device__ __forceinline__ float4 f4add(float4 a, float4 b) {
    return make_float4(a.x + b.x, a.y + b.y, a.z + b.z, a.w + b.w);
}
__device__ __forceinline__ float4 f4fma(float s, float4 a, float4 b) {
    return make_float4(fmaf(s, a.x, b.x), fmaf(s, a.y, b.y),
                       fmaf(s, a.z, b.z), fmaf(s, a.w, b.w));
}
__device__ __forceinline__ float4 shfl_xor32_f4(float4 x) {
    return make_float4(__shfl_xor(x.x, 32, 64), __shfl_xor(x.y, 32, 64),
                       __shfl_xor(x.z, 32, 64), __shfl_xor(x.w, 32, 64));
}

__global__ __launch_bounds__(256) void rgat_fused4_kernel(
    const float* __restrict__ classEmb,   // (V+1, 128)
    const float* __restrict__ reEmb,      // (17, 128)
    const float* __restrict__ anEmbTab,   // (V+NA+1, 128)
    const float* __restrict__ Wc,         // (128,)
    const float* __restrict__ bc,         // (1,)
    const int*  __restrict__ leaves,      // (V, 8)
    const int*  __restrict__ ancestors,   // (V, 8)
    const int*  __restrict__ relations,   // (V, 8)
    const int*  __restrict__ perm,        // (V+1,)
    float*      __restrict__ out)         // (V+1, 128)
{
    const int wid     = blockIdx.x * 4 + (threadIdx.x >> 6);
    const int rowBase = wid * 4;                  // 4 output rows per wave
    if (rowBase > RG_V) return;
    const int lane = threadIdx.x & 63;
    const int h    = lane >> 5;                   // half-wave id
    const int li   = lane & 31;                   // float4 column in a 128-f row

    // ---- one chain-head load resolves all 4 rows' v ----
    int p0, p1, p2, p3;
    if (rowBase + 3 <= RG_V) {
        const int4 pp = *reinterpret_cast<const int4*>(perm + rowBase);
        p0 = pp.x; p1 = pp.y; p2 = pp.z; p3 = pp.w;
    } else {                                      // tail wave only
        p0 = perm[rowBase];
        p1 = (rowBase + 1 <= RG_V) ? perm[rowBase + 1] : RG_V;
        p2 = (rowBase + 2 <= RG_V) ? perm[rowBase + 2] : RG_V;
        p3 = (rowBase + 3 <= RG_V) ? perm[rowBase + 3] : RG_V;
    }
    const int pA[4] = {p0, p1, p2, p3};           // constant-indexed after unroll

    const int4*   anc4 = reinterpret_cast<const int4*>(ancestors);
    const int4*   rel4 = reinterpret_cast<const int4*>(relations);
    const float4* anT  = reinterpret_cast<const float4*>(anEmbTab);
    const float4* reT  = reinterpret_cast<const float4*>(reEmb);
    const float4* clT  = reinterpret_cast<const float4*>(classEmb);
    const float4  w4   = reinterpret_cast<const float4*>(Wc)[li];
    const float   bc0  = bc[0];

    #pragma unroll
    for (int t = 0; t < 2; ++t) {                 // two 2-row tiles per wave
        const int r0 = rowBase + 2 * t;
        if (r0 > RG_V) break;                     // wave-uniform
        const bool have1  = (r0 + 1 <= RG_V);
        const int  q0 = pA[2 * t], q1 = pA[2 * t + 1];
        const bool valid0 = (q0 < RG_V);
        const bool valid1 = have1 && (q1 < RG_V);
        const int  v0 = valid0 ? q0 : 0;
        const int  v1 = valid1 ? q1 : 0;

        // ---- index loads (16B each) ----
        const int4 a00 = anc4[v0 * 2], a01 = anc4[v0 * 2 + 1];
        const int4 a10 = anc4[v1 * 2], a11 = anc4[v1 * 2 + 1];
        const int4 r00 = rel4[v0 * 2], r01 = rel4[v0 * 2 + 1];
        const int4 r10 = rel4[v1 * 2], r11 = rel4[v1 * 2 + 1];
        const int  lv0 = leaves[v0 * RG_L];
        const int  lv1 = leaves[v1 * RG_L];

        // per-lane parity pick (explicit ?:, no runtime array indexing)
        const int ia00 = h ? a00.y : a00.x, ia01 = h ? a00.w : a00.z;
        const int ia02 = h ? a01.y : a01.x, ia03 = h ? a01.w : a01.z;
        const int ia10 = h ? a10.y : a10.x, ia11 = h ? a10.w : a10.z;
        const int ia12 = h ? a11.y : a11.x, ia13 = h ? a11.w : a11.z;
        const int ir00 = h ? r00.y : r00.x, ir01 = h ? r00.w : r00.z;
        const int ir02 = h ? r01.y : r01.x, ir03 = h ? r01.w : r01.z;
        const int ir10 = h ? r10.y : r10.x, ir11 = h ? r10.w : r10.z;
        const int ir12 = h ? r11.y : r11.x, ir13 = h ? r11.w : r11.z;

        // ---- gathers: 1KiB per instruction (2 embedding rows each) ----
        const float4 gA00 = anT[(size_t)ia00 * 32 + li];
        const float4 gA01 = anT[(size_t)ia01 * 32 + li];
        const float4 gA02 = anT[(size_t)ia02 * 32 + li];
        const float4 gA03 = anT[(size_t)ia03 * 32 + li];
        const float4 gA10 = anT[(size_t)ia10 * 32 + li];
        const float4 gA11 = anT[(size_t)ia11 * 32 + li];
        const float4 gA12 = anT[(size_t)ia12 * 32 + li];
        const float4 gA13 = anT[(size_t)ia13 * 32 + li];
        const float4 gR00 = reT[(size_t)ir00 * 32 + li];
        const float4 gR01 = reT[(size_t)ir01 * 32 + li];
        const float4 gR02 = reT[(size_t)ir02 * 32 + li];
        const float4 gR03 = reT[(size_t)ir03 * 32 + li];
        const float4 gR10 = reT[(size_t)ir10 * 32 + li];
        const float4 gR11 = reT[(size_t)ir11 * 32 + li];
        const float4 gR12 = reT[(size_t)ir12 * 32 + li];
        const float4 gR13 = reT[(size_t)ir13 * 32 + li];
        const float4 c4   = clT[(size_t)(h ? lv1 : lv0) * 32 + li];

        // ---- parity-partial sums ----
        float4 accA0 = f4add(f4add(gA00, gA01), f4add(gA02, gA03));
        float4 accA1 = f4add(f4add(gA10, gA11), f4add(gA12, gA13));
        float4 accR0 = f4add(f4add(gR00, gR01), f4add(gR02, gR03));
        float4 accR1 = f4add(f4add(gR10, gR11), f4add(gR12, gR13));

        // ---- per-half dot(classEmb[leaf0], Wc) ----
        float part = c4.x * w4.x + c4.y * w4.y + c4.z * w4.z + c4.w * w4.w;
        #pragma unroll
        for (int off = 16; off >= 1; off >>= 1)
            part += __shfl_xor(part, off, 64);
        const float coe = part + bc0;

        // ---- merge parities: one 32-xor swap serves both rows ----
        float4 oxA = shfl_xor32_f4(h ? accA0 : accA1);
        float4 oxR = shfl_xor32_f4(h ? accR0 : accR1);
        float4 myA = f4add(h ? accA1 : accA0, oxA);
        float4 myR = f4add(h ? accR1 : accR0, oxR);

        float4 res = f4fma(coe, myR, myA);
        const bool validOwn = h ? valid1 : valid0;
        if (!validOwn) res = make_float4(0.f, 0.f, 0.f, 0.f);

        // ---- full-wave contiguous 1KiB nontemporal store ----
        if (h == 0 || have1) {
            float4* dst = reinterpret_cast<float4*>(out) + (size_t)r0 * 32 + lane;
            __builtin_nontemporal_store(*reinterpret_cast<f32x4_native*>(&res),
                                        reinterpret_cast<f32x4_native*>(dst));
        }
    }
}

extern "C" void kernel_launch(void* const* d_in, const int* in_sizes, int n_in,
                              void* d_out, int out_size, void* d_ws, size_t ws_size,
                              hipStream_t stream) {
    // 0 dxEmb (dead), 1 classEmb, 2 reEmb, 3 anEmbTab, 4-7 W1/b1/W2/b2 (dead),
    // 8 Wc, 9 bc, 10 leaves, 11 ancestors, 12 relations, 13 permute_index
    const float* classEmb  = (const float*)d_in[1];
    const float* reEmb     = (const float*)d_in[2];
    const float* anEmbTab  = (const float*)d_in[3];
    const float* Wc        = (const float*)d_in[8];
    const float* bc        = (const float*)d_in[9];
    const int*   leaves    = (const int*)d_in[10];
    const int*   ancestors = (const int*)d_in[11];
    const int*   relations = (const int*)d_in[12];
    const int*   perm      = (const int*)d_in[13];
    float*       out       = (float*)d_out;

    const int waves  = (RG_V + 1 + 3) / 4;   // 4 rows per wave -> 12501 waves
    const int blocks = (waves + 3) / 4;      // 4 waves per 256-thread block

    rgat_fused4_kernel<<<blocks, 256, 0, stream>>>(
        classEmb, reEmb, anEmbTab, Wc, bc,
        leaves, ancestors, relations, perm, out);
}

// Round 11
// 153.864 us; speedup vs baseline: 1.0453x; 1.0219x over previous
//
#include <hip/hip_runtime.h>

// class_aware_rgat — MI355X (round 10: resubmit of round-9; broker timeout,
// never measured).
//
// Live math (softmax over size-1 axis == 1 => MLP path dead):
//   v = perm[i];  out[i] = sum_l anEmbTab[anc[v,l]] + coe(v) * sum_l reEmb[rel[v,l]]
//   coe(v) = dot(classEmb[leaves[v,0]], Wc) + bc ;  out[i] = 0 if v == V
//
// History: r4 2-row 41.5us; r5 coeTab+LDS-rel ~40.5+6 (dead L1/TA theory);
// r8 4-row 41.5us. Constant across all: VGPR_Count=36 => compiler consumes
// loads early (~6 in flight), defeating every source-level ILP attempt.
// This round: asm "+v" fence forces all 17 gathers (8 anc + 8 rel + class)
// simultaneously live -> one vmcnt drain after full issue; launch_bounds
// (256,4) allows ~128 VGPR. In-flight bytes/wave ~6KB -> ~17KB.

#define RG_V  50000
#define RG_L  8

typedef float f32x4 __attribute__((ext_vector_type(4)));

__device__ __forceinline__ f32x4 f4fma(float s, f32x4 a, f32x4 b) {
    f32x4 r;
    r.x = fmaf(s, a.x, b.x); r.y = fmaf(s, a.y, b.y);
    r.z = fmaf(s, a.z, b.z); r.w = fmaf(s, a.w, b.w);
    return r;
}
__device__ __forceinline__ f32x4 shfl_xor32_f4(f32x4 x) {
    f32x4 r;
    r.x = __shfl_xor(x.x, 32, 64); r.y = __shfl_xor(x.y, 32, 64);
    r.z = __shfl_xor(x.z, 32, 64); r.w = __shfl_xor(x.w, 32, 64);
    return r;
}

__global__ __launch_bounds__(256, 4) void rgat_mlp_kernel(
    const float* __restrict__ classEmb,   // (V+1, 128)
    const float* __restrict__ reEmb,      // (17, 128)
    const float* __restrict__ anEmbTab,   // (V+NA+1, 128)
    const float* __restrict__ Wc,         // (128,)
    const float* __restrict__ bc,         // (1,)
    const int*  __restrict__ leaves,      // (V, 8)
    const int*  __restrict__ ancestors,   // (V, 8)
    const int*  __restrict__ relations,   // (V, 8)
    const int*  __restrict__ perm,        // (V+1,)
    float*      __restrict__ out)         // (V+1, 128)
{
    const int wid  = blockIdx.x * 4 + (threadIdx.x >> 6);
    const int row0 = wid * 2;                     // 2 output rows per wave
    if (row0 > RG_V) return;
    const int lane = threadIdx.x & 63;
    const int h    = lane >> 5;                   // half-wave id
    const int li   = lane & 31;                   // float4 column in a row
    const bool have1 = (row0 + 1 <= RG_V);

    const int p0 = perm[row0];
    const int p1 = have1 ? perm[row0 + 1] : 0;
    const bool valid0 = (p0 < RG_V);
    const bool valid1 = have1 && (p1 < RG_V);
    const int v0 = valid0 ? p0 : 0;
    const int v1 = valid1 ? p1 : 0;

    // ---- index loads (16B each; v*8 ints is 32B aligned) ----
    const int4* anc4 = reinterpret_cast<const int4*>(ancestors);
    const int4* rel4 = reinterpret_cast<const int4*>(relations);
    const int4 a00 = anc4[v0 * 2], a01 = anc4[v0 * 2 + 1];
    const int4 a10 = anc4[v1 * 2], a11 = anc4[v1 * 2 + 1];
    const int4 r00 = rel4[v0 * 2], r01 = rel4[v0 * 2 + 1];
    const int4 r10 = rel4[v1 * 2], r11 = rel4[v1 * 2 + 1];
    const int lv0 = leaves[v0 * RG_L];
    const int lv1 = leaves[v1 * RG_L];

    // per-lane parity pick (explicit ?:, no runtime array indexing)
    const int ia00 = h ? a00.y : a00.x, ia01 = h ? a00.w : a00.z;
    const int ia02 = h ? a01.y : a01.x, ia03 = h ? a01.w : a01.z;
    const int ia10 = h ? a10.y : a10.x, ia11 = h ? a10.w : a10.z;
    const int ia12 = h ? a11.y : a11.x, ia13 = h ? a11.w : a11.z;
    const int ir00 = h ? r00.y : r00.x, ir01 = h ? r00.w : r00.z;
    const int ir02 = h ? r01.y : r01.x, ir03 = h ? r01.w : r01.z;
    const int ir10 = h ? r10.y : r10.x, ir11 = h ? r10.w : r10.z;
    const int ir12 = h ? r11.y : r11.x, ir13 = h ? r11.w : r11.z;

    const f32x4* anT = reinterpret_cast<const f32x4*>(anEmbTab);
    const f32x4* reT = reinterpret_cast<const f32x4*>(reEmb);
    const f32x4* clT = reinterpret_cast<const f32x4*>(classEmb);

    // ---- issue ALL 17 gathers; each is a full-wave 1KiB instruction ----
    f32x4 gA00 = anT[(size_t)ia00 * 32 + li];
    f32x4 gA01 = anT[(size_t)ia01 * 32 + li];
    f32x4 gA02 = anT[(size_t)ia02 * 32 + li];
    f32x4 gA03 = anT[(size_t)ia03 * 32 + li];
    f32x4 gA10 = anT[(size_t)ia10 * 32 + li];
    f32x4 gA11 = anT[(size_t)ia11 * 32 + li];
    f32x4 gA12 = anT[(size_t)ia12 * 32 + li];
    f32x4 gA13 = anT[(size_t)ia13 * 32 + li];
    f32x4 gR00 = reT[(size_t)ir00 * 32 + li];
    f32x4 gR01 = reT[(size_t)ir01 * 32 + li];
    f32x4 gR02 = reT[(size_t)ir02 * 32 + li];
    f32x4 gR03 = reT[(size_t)ir03 * 32 + li];
    f32x4 gR10 = reT[(size_t)ir10 * 32 + li];
    f32x4 gR11 = reT[(size_t)ir11 * 32 + li];
    f32x4 gR12 = reT[(size_t)ir12 * 32 + li];
    f32x4 gR13 = reT[(size_t)ir13 * 32 + li];
    f32x4 c4   = clT[(size_t)(h ? lv1 : lv0) * 32 + li];

    // ---- MLP fence: force all 17 results simultaneously live (68 VGPRs).
    // Compiler must issue every load before this point and drain vmcnt once.
    asm volatile("" : "+v"(gA00), "+v"(gA01), "+v"(gA02), "+v"(gA03),
                      "+v"(gA10), "+v"(gA11), "+v"(gA12), "+v"(gA13),
                      "+v"(gR00), "+v"(gR01), "+v"(gR02), "+v"(gR03),
                      "+v"(gR10), "+v"(gR11), "+v"(gR12), "+v"(gR13),
                      "+v"(c4));

    const f32x4 w4  = reinterpret_cast<const f32x4*>(Wc)[li];
    const float bc0 = bc[0];

    // ---- parity-partial sums ----
    f32x4 accA0 = (gA00 + gA01) + (gA02 + gA03);
    f32x4 accA1 = (gA10 + gA11) + (gA12 + gA13);
    f32x4 accR0 = (gR00 + gR01) + (gR02 + gR03);
    f32x4 accR1 = (gR10 + gR11) + (gR12 + gR13);

    // ---- per-half dot(classEmb[leaf0], Wc) ----
    float part = c4.x * w4.x + c4.y * w4.y + c4.z * w4.z + c4.w * w4.w;
    #pragma unroll
    for (int off = 16; off >= 1; off >>= 1)
        part += __shfl_xor(part, off, 64);
    const float coe = part + bc0;

    // ---- merge parities: one 32-xor swap serves both rows ----
    f32x4 oxA = shfl_xor32_f4(h ? accA0 : accA1);
    f32x4 oxR = shfl_xor32_f4(h ? accR0 : accR1);
    f32x4 myA = (h ? accA1 : accA0) + oxA;
    f32x4 myR = (h ? accR1 : accR0) + oxR;

    f32x4 res = f4fma(coe, myR, myA);
    const bool validOwn = h ? valid1 : valid0;
    if (!validOwn) { res.x = 0.f; res.y = 0.f; res.z = 0.f; res.w = 0.f; }

    // ---- full-wave contiguous 1KiB nontemporal store ----
    if (h == 0 || have1) {
        f32x4* dst = reinterpret_cast<f32x4*>(out) + (size_t)row0 * 32 + lane;
        __builtin_nontemporal_store(res, dst);
    }
}

extern "C" void kernel_launch(void* const* d_in, const int* in_sizes, int n_in,
                              void* d_out, int out_size, void* d_ws, size_t ws_size,
                              hipStream_t stream) {
    // 0 dxEmb (dead), 1 classEmb, 2 reEmb, 3 anEmbTab, 4-7 W1/b1/W2/b2 (dead),
    // 8 Wc, 9 bc, 10 leaves, 11 ancestors, 12 relations, 13 permute_index
    const float* classEmb  = (const float*)d_in[1];
    const float* reEmb     = (const float*)d_in[2];
    const float* anEmbTab  = (const float*)d_in[3];
    const float* Wc        = (const float*)d_in[8];
    const float* bc        = (const float*)d_in[9];
    const int*   leaves    = (const int*)d_in[10];
    const int*   ancestors = (const int*)d_in[11];
    const int*   relations = (const int*)d_in[12];
    const int*   perm      = (const int*)d_in[13];
    float*       out       = (float*)d_out;

    const int waves  = (RG_V + 1 + 1) / 2;   // 2 rows per wave -> 25001 waves
    const int blocks = (waves + 3) / 4;      // 4 waves per 256-thread block

    rgat_mlp_kernel<<<blocks, 256, 0, stream>>>(
        classEmb, reEmb, anEmbTab, Wc, bc,
        leaves, ancestors, relations, perm, out);
}